// Round 13
// baseline (514.476 us; speedup 1.0000x reference)
//
#include <hip/hip_runtime.h>
#include <cmath>

constexpr int cB = 4, cN = 256, cD = 240, cH = 8, cFF = 1024, cL = 4;
constexpr int cHD = 30;
constexpr int cS2 = 515;              // suffix-only sequence (prefix is dead code)
constexpr int cBS2 = cB * cS2;        // 2060
constexpr int cKp = 256;              // padded K for D-sized contractions
constexpr int cSP2 = 576;             // padded suffix length (9 tiles of 64)
constexpr float EPSF = 1e-5f;

typedef __bf16 bf16x8 __attribute__((ext_vector_type(8)));
typedef float f32x4 __attribute__((ext_vector_type(4)));

__device__ inline unsigned short f2bf(float f) {
    unsigned int u = __builtin_bit_cast(unsigned int, f);
    unsigned int r = (u + 0x7fffu + ((u >> 16) & 1u)) >> 16;
    return (unsigned short)r;
}

// =============== setup: weight convert + trig + zero-init + suffix embed, one dispatch =====
constexpr int R1 = 4 * cL * 65536;          // wqkv convert
constexpr int R2 = R1 + cL * 1024 * 256;    // w1p
constexpr int R3 = R2 + cL * 256 * 1024;    // w2p
constexpr int R4 = R3 + cBS2 * cD;          // embed (suffix only)
constexpr int R5 = R4 + cBS2 * 15;          // rope trig table
constexpr size_t qkvN = (size_t)cB * cH * cSP2 * 32;
constexpr int nSpan32 = (int)(3 * qkvN / 2);
constexpr int R6 = R5 + nSpan32;            // q/k/vT zero span (u32)
constexpr int R7 = R6 + cBS2 * 8;           // pad cols of 3 activation bufs (u32 each)

__global__ __launch_bounds__(256) void setup_all(
    const float* __restrict__ Wq, const float* __restrict__ Wk,
    const float* __restrict__ Wv, const float* __restrict__ Wo,
    const float* __restrict__ W1, const float* __restrict__ W2,
    const float* __restrict__ hand_t, const float* __restrict__ head_t,
    const float* __restrict__ state_t,
    const float* __restrict__ hand_pose_t, const float* __restrict__ head_pose_t,
    const float* __restrict__ ch_t, const float* __restrict__ cd_t,
    unsigned short* __restrict__ wqkv, unsigned short* __restrict__ w1p,
    unsigned short* __restrict__ w2p,
    float* __restrict__ src, unsigned short* __restrict__ sbf,
    float2* __restrict__ trig,
    unsigned int* __restrict__ qkvspan,
    unsigned short* __restrict__ padA, unsigned short* __restrict__ padB,
    unsigned short* __restrict__ padC)
{
    int idx = blockIdx.x * 256 + threadIdx.x;
    if (idx < R1) {
        int which = idx >> 18;
        const float* W = (which == 0) ? Wq : (which == 1) ? Wk : (which == 2) ? Wv : Wo;
        int rem = idx & 262143;
        int m = rem >> 16;
        int rc = rem & 65535;
        int r = rc >> 8, c = rc & 255;
        float v = (r < 240 && c < 240) ? W[((size_t)m * 240 + r) * 240 + c] : 0.f;
        wqkv[idx] = f2bf(v);
    } else if (idx < R2) {
        int rem = idx - R1;
        int m = rem >> 18;
        int rc = rem & 262143;
        int r = rc >> 8, c = rc & 255;
        float v = (c < 240) ? W1[((size_t)m * 1024 + r) * 240 + c] : 0.f;
        w1p[rem] = f2bf(v);
    } else if (idx < R3) {
        int rem = idx - R2;
        int m = rem >> 18;
        int rc = rem & 262143;
        int r = rc >> 10, c = rc & 1023;
        float v = (r < 240) ? W2[((size_t)m * 240 + r) * 1024 + c] : 0.f;
        w2p[rem] = f2bf(v);
    } else if (idx < R4) {
        int rem = idx - R3;
        int d = rem % cD;
        int r = rem / cD;
        int b = r / cS2, s = r % cS2;
        const float* p; int off;
        if (s == 0)          { p = state_t;      off = b * cD + d; }
        else if (s == 1)     { p = hand_pose_t;  off = b * cD + d; }
        else if (s == 2)     { p = head_pose_t;  off = b * cD + d; }
        else if (s < 259)    { p = hand_t;       off = (b * cN + (s - 3)) * cD + d; }
        else                 { p = head_t;       off = (b * cN + (s - 259)) * cD + d; }
        float v = p[off];
        src[rem] = v;
        sbf[(size_t)r * cKp + d] = f2bf(v);
    } else if (idx < R5) {
        int rem = idx - R4;
        int r = rem / 15, pair = rem - r * 15;
        int b = r / cS2, s = r % cS2;
        int a = pair / 5, j = pair - a * 5;
        float coord = 0.f;
        if (s >= 3 && s < 259)       coord = ch_t[(b * cN + (s - 3)) * 3 + a];
        else if (s >= 259)           coord = cd_t[(b * cN + (s - 259)) * 3 + a];
        float inv = __expf(-1.8420680743952367f * (float)j);
        float sn, co;
        sincosf(coord * inv, &sn, &co);
        trig[rem] = make_float2(co, sn);
    } else if (idx < R6) {
        qkvspan[idx - R5] = 0u;
    } else if (idx < R7) {
        int rem = idx - R6;
        int r = rem >> 3, j = rem & 7;
        ((unsigned int*)(padA + (size_t)r * 256 + 240))[j] = 0u;
        ((unsigned int*)(padB + (size_t)r * 256 + 240))[j] = 0u;
        ((unsigned int*)(padC + (size_t)r * 256 + 240))[j] = 0u;
    }
}

// ======== MFMA GEMM core, BM=64/BN=64, BK=64, wave tile 32x32 ========
#define GEMM_CORE64(A_PTR, W_PTR, M_, KA_, NK_)                                               \
    __shared__ unsigned short Al[64][72];                                                     \
    __shared__ unsigned short Bl[64][72];                                                     \
    const int tid = threadIdx.x;                                                              \
    const int lane = tid & 63;                                                                \
    const int w = tid >> 6;                                                                   \
    const int wm = w >> 1, wn = w & 1;                                                        \
    const int lrow = lane & 15, kq = lane >> 4;                                               \
    const int colBase = blockIdx.x * 64;                                                      \
    const int sRow = tid >> 2;                                                                \
    const int sC = (tid & 3) * 16;                                                            \
    const int ar0 = min(rowBase + sRow, M_ - 1);                                              \
    const int wr = colBase + sRow;                                                            \
    const unsigned short* a0p = A_PTR + (size_t)ar0 * KA_ + sC;                               \
    const unsigned short* wp  = W_PTR + (size_t)wr * KA_ + sC;                                \
    f32x4 acc[2][2] = {};                                                                     \
    int4 rA0a = *(const int4*)a0p, rA0b = *(const int4*)(a0p + 8);                            \
    int4 rBa  = *(const int4*)wp,  rBb  = *(const int4*)(wp + 8);                             \
    for (int ks = 0; ks < NK_; ++ks) {                                                        \
        __syncthreads();                                                                      \
        *(int4*)&Al[sRow][sC]     = rA0a;                                                     \
        *(int4*)&Al[sRow][sC + 8] = rA0b;                                                     \
        *(int4*)&Bl[sRow][sC]     = rBa;                                                      \
        *(int4*)&Bl[sRow][sC + 8] = rBb;                                                      \
        __syncthreads();                                                                      \
        if (ks + 1 < NK_) {                                                                   \
            int kk = (ks + 1) * 64;                                                           \
            rA0a = *(const int4*)(a0p + kk); rA0b = *(const int4*)(a0p + kk + 8);             \
            rBa  = *(const int4*)(wp + kk);  rBb  = *(const int4*)(wp + kk + 8);              \
        }                                                                                     \
        _Pragma("unroll")                                                                     \
        for (int sub = 0; sub < 2; ++sub) {                                                   \
            bf16x8 af[2], bfr[2];                                                             \
            _Pragma("unroll")                                                                 \
            for (int i = 0; i < 2; ++i)                                                       \
                af[i] = *(const bf16x8*)&Al[wm * 32 + i * 16 + lrow][sub * 32 + kq * 8];      \
            _Pragma("unroll")                                                                 \
            for (int j = 0; j < 2; ++j)                                                       \
                bfr[j] = *(const bf16x8*)&Bl[wn * 32 + j * 16 + lrow][sub * 32 + kq * 8];     \
            _Pragma("unroll")                                                                 \
            for (int i = 0; i < 2; ++i)                                                       \
                _Pragma("unroll")                                                             \
                for (int j = 0; j < 2; ++j)                                                   \
                    acc[i][j] = __builtin_amdgcn_mfma_f32_16x16x32_bf16(af[i], bfr[j], acc[i][j], 0, 0, 0); \
        }                                                                                     \
    }

// ------- QKV GEMM (BM=64) with fused RoPE; bf16 q,k (BH,SP2,32) and V^T (BH,32,SP2) -------
__global__ __launch_bounds__(256) void gemm_qkv_rope(
    const unsigned short* __restrict__ A,
    const unsigned short* __restrict__ Wqp, const unsigned short* __restrict__ Wkp,
    const unsigned short* __restrict__ Wvp,
    const float* __restrict__ bq, const float* __restrict__ bk, const float* __restrict__ bv,
    const float2* __restrict__ trig,
    unsigned short* __restrict__ qbf, unsigned short* __restrict__ kbf,
    unsigned short* __restrict__ vtbf)
{
    const int z = blockIdx.z;
    const unsigned short* Wsel = (z == 0) ? Wqp : (z == 1) ? Wkp : Wvp;
    const float* bias = (z == 0) ? bq : (z == 1) ? bk : bv;
    const int rowBase = blockIdx.y * 64;
    GEMM_CORE64(A, Wsel, cBS2, cKp, 4)
    if (z == 2) {
#pragma unroll
        for (int i = 0; i < 2; ++i) {
#pragma unroll
            for (int j = 0; j < 2; ++j) {
                int col = colBase + wn * 32 + j * 16 + lrow;
                if (col >= cD) continue;
                float bcol = bias[col];
                int hh = col / cHD, hd = col % cHD;
                f32x4 vv = acc[i][j];
                int row0 = rowBase + wm * 32 + i * 16 + kq * 4;
                int b0 = row0 / cS2, s0 = row0 - b0 * cS2;
                if (row0 + 3 < cBS2 && s0 + 3 < cS2) {
                    unsigned int lo = (unsigned)f2bf(vv[0] + bcol) | ((unsigned)f2bf(vv[1] + bcol) << 16);
                    unsigned int hi = (unsigned)f2bf(vv[2] + bcol) | ((unsigned)f2bf(vv[3] + bcol) << 16);
                    size_t base = ((size_t)(b0 * cH + hh) * 32 + hd) * cSP2 + s0;
                    *(unsigned int*)&vtbf[base]     = lo;
                    *(unsigned int*)&vtbf[base + 2] = hi;
                } else {
#pragma unroll
                    for (int r = 0; r < 4; ++r) {
                        int row = row0 + r;
                        if (row >= cBS2) continue;
                        int bb = row / cS2, ss = row - bb * cS2;
                        vtbf[((size_t)(bb * cH + hh) * 32 + hd) * cSP2 + ss] = f2bf(vv[r] + bcol);
                    }
                }
            }
        }
    } else {
        unsigned short* dst = (z == 0) ? qbf : kbf;
#pragma unroll
        for (int i = 0; i < 2; ++i) {
#pragma unroll
            for (int j = 0; j < 2; ++j) {
                int col = colBase + wn * 32 + j * 16 + lrow;
                bool colok = col < cD;
                int cc = colok ? col : 0;
                float bcol = colok ? bias[cc] : 0.f;
                int hh = cc / cHD, hd = cc % cHD;
                int a3 = hd / 10, jj = (hd % 10) >> 1;
                int pair = a3 * 5 + jj;
                f32x4 vv = acc[i][j];
#pragma unroll
                for (int r = 0; r < 4; ++r) {
                    int row = rowBase + wm * 32 + i * 16 + kq * 4 + r;
                    bool rowok = row < cBS2;
                    int rowc = rowok ? row : 0;
                    float val = vv[r] + bcol;
                    float pval = __shfl_xor(val, 1);   // partner col (pairs are adjacent lanes)
                    float2 t = trig[rowc * 15 + pair];
                    float outv = (hd & 1) ? (pval * t.y + val * t.x) : (val * t.x - pval * t.y);
                    if (colok && rowok) {
                        int b = rowc / cS2, s = rowc - b * cS2;
                        dst[((size_t)(b * cH + hh) * cSP2 + s) * 32 + hd] = f2bf(outv);
                    }
                }
            }
        }
    }
}

// ------- MFMA flash attention (unmasked suffix), kv-split x4: 16 q-rows/block -------
__global__ __launch_bounds__(256) void attn_mfma(
    const unsigned short* __restrict__ qbf, const unsigned short* __restrict__ kbf,
    const unsigned short* __restrict__ vtbf, unsigned short* __restrict__ outb)
{
    __shared__ unsigned short Pl[4][16][72];
    __shared__ float Ol[4][16][33];
    __shared__ float Ml[4][16];
    __shared__ float Ll[4][16];
    const int tid = threadIdx.x, lane = tid & 63, w = tid >> 6;
    const int bh = blockIdx.y, b = bh >> 3, h = bh & 7;
    const int qbase = blockIdx.x * 16;
    const int lr = lane & 15, lg = lane >> 4;
    const float scl = 0.18257418583505536f; // 1/sqrt(30)
    const f32x4 czero = {0.f, 0.f, 0.f, 0.f};
    bf16x8 qf = *(const bf16x8*)&qbf[((size_t)bh * cSP2 + qbase + lr) * 32 + lg * 8];
    float m[4], l[4];
    f32x4 o0 = czero, o1 = czero;
#pragma unroll
    for (int r = 0; r < 4; ++r) { m[r] = -3.0e38f; l[r] = 0.f; }
    const int ts = (w * 9) / 4;
    const int te = ((w + 1) * 9) / 4;
    for (int tt = ts; tt < te; ++tt) {
        const int kb = tt * 64;
        f32x4 c[4];
#pragma unroll
        for (int t = 0; t < 4; ++t) {
            bf16x8 kf = *(const bf16x8*)&kbf[((size_t)bh * cSP2 + kb + 16 * t + lr) * 32 + lg * 8];
            c[t] = __builtin_amdgcn_mfma_f32_16x16x32_bf16(qf, kf, czero, 0, 0, 0);
        }
#pragma unroll
        for (int t = 0; t < 4; ++t) {
            bool koob = (kb + 16 * t + lr) >= cS2;
#pragma unroll
            for (int r = 0; r < 4; ++r)
                c[t][r] = koob ? -3.0e38f : c[t][r] * scl;
        }
        float mx[4];
#pragma unroll
        for (int r = 0; r < 4; ++r)
            mx[r] = fmaxf(fmaxf(c[0][r], c[1][r]), fmaxf(c[2][r], c[3][r]));
#pragma unroll
        for (int off = 1; off < 16; off <<= 1)
#pragma unroll
            for (int r = 0; r < 4; ++r)
                mx[r] = fmaxf(mx[r], __shfl_xor(mx[r], off));
        float corr[4], me[4], ps[4];
#pragma unroll
        for (int r = 0; r < 4; ++r) {
            float mn = fmaxf(m[r], mx[r]);
            corr[r] = __expf(m[r] - mn);
            m[r] = mn;
            me[r] = fmaxf(mn, -1.0e30f);
            ps[r] = 0.f;
        }
#pragma unroll
        for (int t = 0; t < 4; ++t)
#pragma unroll
            for (int r = 0; r < 4; ++r) {
                float p = __expf(c[t][r] - me[r]);
                c[t][r] = p;
                ps[r] += p;
            }
#pragma unroll
        for (int off = 1; off < 16; off <<= 1)
#pragma unroll
            for (int r = 0; r < 4; ++r)
                ps[r] += __shfl_xor(ps[r], off);
#pragma unroll
        for (int r = 0; r < 4; ++r) {
            l[r] = l[r] * corr[r] + ps[r];
            o0[r] *= corr[r];
            o1[r] *= corr[r];
        }
#pragma unroll
        for (int t = 0; t < 4; ++t)
#pragma unroll
            for (int r = 0; r < 4; ++r)
                Pl[w][lg * 4 + r][16 * t + lr] = f2bf(c[t][r]);
#pragma unroll
        for (int c2 = 0; c2 < 2; ++c2) {
            bf16x8 pa  = *(const bf16x8*)&Pl[w][lr][c2 * 32 + lg * 8];
            bf16x8 bv0 = *(const bf16x8*)&vtbf[((size_t)bh * 32 + lr) * cSP2 + kb + c2 * 32 + lg * 8];
            bf16x8 bv1 = *(const bf16x8*)&vtbf[((size_t)bh * 32 + 16 + lr) * cSP2 + kb + c2 * 32 + lg * 8];
            o0 = __builtin_amdgcn_mfma_f32_16x16x32_bf16(pa, bv0, o0, 0, 0, 0);
            o1 = __builtin_amdgcn_mfma_f32_16x16x32_bf16(pa, bv1, o1, 0, 0, 0);
        }
    }
#pragma unroll
    for (int r = 0; r < 4; ++r) {
        int row = lg * 4 + r;
        if (lr == 0) { Ml[w][row] = m[r]; Ll[w][row] = l[r]; }
        Ol[w][row][lr]      = o0[r];
        Ol[w][row][16 + lr] = o1[r];
    }
    __syncthreads();
    if (w == 0) {
        const int col = lane & 31, half = lane >> 5;
#pragma unroll
        for (int rr = 0; rr < 8; ++rr) {
            int row = half * 8 + rr;
            float M = fmaxf(fmaxf(Ml[0][row], Ml[1][row]), fmaxf(Ml[2][row], Ml[3][row]));
            float Lt = 0.f, Ot = 0.f;
#pragma unroll
            for (int ww = 0; ww < 4; ++ww) {
                float cc = __expf(Ml[ww][row] - M);
                Lt += Ll[ww][row] * cc;
                Ot += Ol[ww][row][col] * cc;
            }
            int qq = qbase + row;
            if (qq < cS2 && col < cHD)
                outb[((size_t)(b * cS2 + qq)) * cKp + h * cHD + col] = f2bf(Ot / Lt);
        }
    }
}

// ------- full-width fused GEMM + bias + residual + LayerNorm (BM=64, BN=240) -------
// Swapped-operand MFMA: acc col-index = A-row (lane-local row) so LN is wave-local.
// out = LN(A @ W^T + bias + resf) -> outF f32 (ld 240) [+ outB bf16 (ld 256)]
template<int KA, int NK>
__global__ __launch_bounds__(256) void gemm_rowln(
    const unsigned short* __restrict__ A, const unsigned short* __restrict__ W,
    const float* __restrict__ bias, const float* __restrict__ resf,
    const float* __restrict__ g, const float* __restrict__ be,
    float* __restrict__ outF, unsigned short* __restrict__ outB)
{
    __shared__ unsigned short Al[64][72];
    __shared__ unsigned short Wl[240][72];
    const int tid = threadIdx.x;
    const int lane = tid & 63;
    const int w = tid >> 6;
    const int lrow = lane & 15, kq = lane >> 4;
    const int rowBase = blockIdx.x * 64;
    const int aRow = tid >> 2, aC = (tid & 3) * 16;
    const unsigned short* ap = A + (size_t)min(rowBase + aRow, cBS2 - 1) * KA + aC;
    const unsigned short* wp = W + (size_t)tid * KA;
    f32x4 acc[15] = {};
    int4 rA0 = *(const int4*)ap, rA1 = *(const int4*)(ap + 8);
    int4 rW[8];
    if (tid < 240) {
#pragma unroll
        for (int i = 0; i < 8; ++i) rW[i] = *(const int4*)(wp + i * 8);
    }
    for (int ks = 0; ks < NK; ++ks) {
        __syncthreads();
        *(int4*)&Al[aRow][aC]     = rA0;
        *(int4*)&Al[aRow][aC + 8] = rA1;
        if (tid < 240) {
#pragma unroll
            for (int i = 0; i < 8; ++i) *(int4*)&Wl[tid][i * 8] = rW[i];
        }
        __syncthreads();
        if (ks + 1 < NK) {
            int kk = (ks + 1) * 64;
            rA0 = *(const int4*)(ap + kk); rA1 = *(const int4*)(ap + kk + 8);
            if (tid < 240) {
#pragma unroll
                for (int i = 0; i < 8; ++i) rW[i] = *(const int4*)(wp + kk + i * 8);
            }
        }
#pragma unroll
        for (int sub = 0; sub < 2; ++sub) {
            bf16x8 av = *(const bf16x8*)&Al[w * 16 + lrow][sub * 32 + kq * 8];
#pragma unroll
            for (int f = 0; f < 15; ++f) {
                bf16x8 wf = *(const bf16x8*)&Wl[f * 16 + lrow][sub * 32 + kq * 8];
                acc[f] = __builtin_amdgcn_mfma_f32_16x16x32_bf16(wf, av, acc[f], 0, 0, 0);
            }
        }
    }
    // epilogue: lane owns row rowBase + w*16 + lrow, cols f*16 + kq*4 + {0..3}
    const int row = rowBase + w * 16 + lrow;
    const bool rok = row < cBS2;
    const int rowc = min(row, cBS2 - 1);
    float s1 = 0.f, sq = 0.f;
#pragma unroll
    for (int f = 0; f < 15; ++f) {
        int col = f * 16 + kq * 4;
        float4 b4 = *(const float4*)(bias + col);
        float4 r4 = *(const float4*)(resf + (size_t)rowc * 240 + col);
        acc[f][0] += b4.x + r4.x;
        acc[f][1] += b4.y + r4.y;
        acc[f][2] += b4.z + r4.z;
        acc[f][3] += b4.w + r4.w;
        s1 += acc[f][0] + acc[f][1] + acc[f][2] + acc[f][3];
        sq += acc[f][0] * acc[f][0] + acc[f][1] * acc[f][1]
            + acc[f][2] * acc[f][2] + acc[f][3] * acc[f][3];
    }
    s1 += __shfl_xor(s1, 16); s1 += __shfl_xor(s1, 32);
    sq += __shfl_xor(sq, 16); sq += __shfl_xor(sq, 32);
    float mean = s1 * (1.0f / cD);
    float rstd = rsqrtf(sq * (1.0f / cD) - mean * mean + EPSF);
    if (rok) {
#pragma unroll
        for (int f = 0; f < 15; ++f) {
            int col = f * 16 + kq * 4;
            float4 g4 = *(const float4*)(g + col);
            float4 e4 = *(const float4*)(be + col);
            float4 y;
            y.x = (acc[f][0] - mean) * rstd * g4.x + e4.x;
            y.y = (acc[f][1] - mean) * rstd * g4.y + e4.y;
            y.z = (acc[f][2] - mean) * rstd * g4.z + e4.z;
            y.w = (acc[f][3] - mean) * rstd * g4.w + e4.w;
            *(float4*)(outF + (size_t)row * 240 + col) = y;
            if (outB) {
                uint2 pk;
                pk.x = (unsigned)f2bf(y.x) | ((unsigned)f2bf(y.y) << 16);
                pk.y = (unsigned)f2bf(y.z) | ((unsigned)f2bf(y.w) << 16);
                *(uint2*)(outB + (size_t)row * cKp + col) = pk;
            }
        }
    }
}

// ------- FF1 GEMM (BM=64): gelu(+bias) -> bf16 (ld 1024) -------
__global__ __launch_bounds__(256) void gemm_ff1(
    const unsigned short* __restrict__ A, const unsigned short* __restrict__ W,
    const float* __restrict__ bias, unsigned short* __restrict__ outB)
{
    const int rowBase = blockIdx.y * 64;
    GEMM_CORE64(A, W, cBS2, cKp, 4)
#pragma unroll
    for (int i = 0; i < 2; ++i) {
#pragma unroll
        for (int j = 0; j < 2; ++j) {
            int col = colBase + wn * 32 + j * 16 + lrow;
            float bcol = bias[col];
            f32x4 v = acc[i][j];
#pragma unroll
            for (int r = 0; r < 4; ++r) {
                int row = rowBase + wm * 32 + i * 16 + kq * 4 + r;
                if (row >= cBS2) continue;
                float t = v[r] + bcol;
                float gl = 0.5f * t * (1.0f + erff(t * 0.70710678118654752f));
                outB[(size_t)row * 1024 + col] = f2bf(gl);
            }
        }
    }
}

extern "C" void kernel_launch(void* const* d_in, const int* in_sizes, int n_in,
                              void* d_out, int out_size, void* d_ws, size_t ws_size,
                              hipStream_t stream) {
    (void)in_sizes; (void)n_in; (void)out_size; (void)ws_size;
    const float* hand_t       = (const float*)d_in[0];
    const float* head_t       = (const float*)d_in[1];
    const float* c_hand_t     = (const float*)d_in[4];
    const float* c_head_t     = (const float*)d_in[5];
    const float* state_t      = (const float*)d_in[8];
    const float* hand_pose_t  = (const float*)d_in[12];
    const float* head_pose_t  = (const float*)d_in[13];
    const float* Wq = (const float*)d_in[14];
    const float* Wk = (const float*)d_in[15];
    const float* Wv = (const float*)d_in[16];
    const float* Wo = (const float*)d_in[17];
    const float* W1 = (const float*)d_in[18];
    const float* W2 = (const float*)d_in[19];
    const float* bq = (const float*)d_in[20];
    const float* bk = (const float*)d_in[21];
    const float* bv = (const float*)d_in[22];
    const float* bo = (const float*)d_in[23];
    const float* b1 = (const float*)d_in[24];
    const float* b2 = (const float*)d_in[25];
    const float* g1 = (const float*)d_in[26];
    const float* be1 = (const float*)d_in[27];
    const float* g2 = (const float*)d_in[28];
    const float* be2 = (const float*)d_in[29];

    // ---- workspace layout ----
    char* p = (char*)d_ws;
    auto alloc_f = [&](size_t n) { float* r = (float*)p; p += n * sizeof(float); return r; };
    auto alloc_h = [&](size_t n) { unsigned short* r = (unsigned short*)p; p += n * sizeof(unsigned short); return r; };
    float* srcb  = alloc_f((size_t)cBS2 * cD);
    float* s2b   = alloc_f((size_t)cBS2 * cD);
    float* trigf = alloc_f((size_t)cBS2 * 15 * 2);
    unsigned short* src_bf  = alloc_h((size_t)cBS2 * cKp);
    unsigned short* s2_bf   = alloc_h((size_t)cBS2 * cKp);
    unsigned short* attn_bf = alloc_h((size_t)cBS2 * cKp);
    unsigned short* ff_bf   = alloc_h((size_t)cBS2 * cFF);
    unsigned short* qbf  = alloc_h(qkvN);
    unsigned short* kbf  = alloc_h(qkvN);
    unsigned short* vtbf = alloc_h(qkvN);
    unsigned short* wqkv = alloc_h((size_t)4 * cL * 65536);
    unsigned short* w1p  = alloc_h((size_t)cL * 1024 * 256);
    unsigned short* w2p  = alloc_h((size_t)cL * 256 * 1024);
    float2* trig = (float2*)trigf;

    // ---- setup (single dispatch) ----
    setup_all<<<(R7 + 255) / 256, 256, 0, stream>>>(
        Wq, Wk, Wv, Wo, W1, W2,
        hand_t, head_t, state_t, hand_pose_t, head_pose_t,
        c_hand_t, c_head_t,
        wqkv, w1p, w2p, srcb, src_bf, trig,
        (unsigned int*)qbf, src_bf, s2_bf, attn_bf);

    const int mT = (cBS2 + 63) / 64;   // 33
    for (int l = 0; l < cL; ++l) {
        const unsigned short* wq_l = wqkv + (size_t)(0 * cL + l) * 65536;
        const unsigned short* wk_l = wqkv + (size_t)(1 * cL + l) * 65536;
        const unsigned short* wv_l = wqkv + (size_t)(2 * cL + l) * 65536;
        const unsigned short* wo_l = wqkv + (size_t)(3 * cL + l) * 65536;
        const unsigned short* w1_l = w1p + (size_t)l * 1024 * 256;
        const unsigned short* w2_l = w2p + (size_t)l * 256 * 1024;
        const float* bq_l = bq + (size_t)l * cD;
        const float* bk_l = bk + (size_t)l * cD;
        const float* bv_l = bv + (size_t)l * cD;
        const float* bo_l = bo + (size_t)l * cD;
        const float* b1_l = b1 + (size_t)l * cFF;
        const float* b2_l = b2 + (size_t)l * cD;
        const float* g1_l = g1 + (size_t)l * cD;
        const float* be1_l = be1 + (size_t)l * cD;
        const float* g2_l = g2 + (size_t)l * cD;
        const float* be2_l = be2 + (size_t)l * cD;

        gemm_qkv_rope<<<dim3(4, mT, 3), 256, 0, stream>>>(
            src_bf, wq_l, wk_l, wv_l, bq_l, bk_l, bv_l, trig, qbf, kbf, vtbf);
        attn_mfma<<<dim3((cS2 + 15) / 16, cB * cH), 256, 0, stream>>>(
            qbf, kbf, vtbf, attn_bf);
        // O-proj + residual + LN1 fused
        gemm_rowln<cKp, 4><<<mT, 256, 0, stream>>>(
            attn_bf, wo_l, bo_l, srcb, g1_l, be1_l, s2b, s2_bf);
        gemm_ff1<<<dim3(16, mT), 256, 0, stream>>>(s2_bf, w1_l, b1_l, ff_bf);
        // FF2 + residual + LN2 fused (last layer writes d_out directly)
        if (l < cL - 1) {
            gemm_rowln<cFF, 16><<<mT, 256, 0, stream>>>(
                ff_bf, w2_l, b2_l, s2b, g2_l, be2_l, srcb, src_bf);
        } else {
            gemm_rowln<cFF, 16><<<mT, 256, 0, stream>>>(
                ff_bf, w2_l, b2_l, s2b, g2_l, be2_l, (float*)d_out, nullptr);
        }
    }
}

// Round 14
// 247.370 us; speedup vs baseline: 2.0798x; 2.0798x over previous
//
#include <hip/hip_runtime.h>
#include <cmath>

constexpr int cB = 4, cN = 256, cD = 240, cH = 8, cFF = 1024, cL = 4;
constexpr int cHD = 30;
constexpr int cS2 = 515;              // suffix-only sequence (prefix is dead code)
constexpr int cBS2 = cB * cS2;        // 2060
constexpr int cKp = 256;              // padded K for D-sized contractions
constexpr int cSP2 = 576;             // padded suffix length (9 tiles of 64)
constexpr float EPSF = 1e-5f;

typedef __bf16 bf16x8 __attribute__((ext_vector_type(8)));
typedef float f32x4 __attribute__((ext_vector_type(4)));

__device__ inline unsigned short f2bf(float f) {
    unsigned int u = __builtin_bit_cast(unsigned int, f);
    unsigned int r = (u + 0x7fffu + ((u >> 16) & 1u)) >> 16;
    return (unsigned short)r;
}

// =============== setup: weight convert + trig + zero-init + suffix embed, one dispatch =====
constexpr int R1 = 4 * cL * 65536;          // wqkv convert
constexpr int R2 = R1 + cL * 1024 * 256;    // w1p
constexpr int R3 = R2 + cL * 256 * 1024;    // w2p
constexpr int R4 = R3 + cBS2 * cD;          // embed (suffix only)
constexpr int R5 = R4 + cBS2 * 15;          // rope trig table
constexpr size_t qkvN = (size_t)cB * cH * cSP2 * 32;  // 589824
constexpr int nSpan32 = (int)(3 * qkvN / 2);
constexpr int R6 = R5 + nSpan32;            // q/k/vT zero span (u32)
constexpr int R7 = R6 + cBS2 * 8;           // pad cols of 3 activation bufs (u32 each)

__global__ __launch_bounds__(256) void setup_all(
    const float* __restrict__ Wq, const float* __restrict__ Wk,
    const float* __restrict__ Wv, const float* __restrict__ Wo,
    const float* __restrict__ W1, const float* __restrict__ W2,
    const float* __restrict__ hand_t, const float* __restrict__ head_t,
    const float* __restrict__ state_t,
    const float* __restrict__ hand_pose_t, const float* __restrict__ head_pose_t,
    const float* __restrict__ ch_t, const float* __restrict__ cd_t,
    unsigned short* __restrict__ wqkv, unsigned short* __restrict__ w1p,
    unsigned short* __restrict__ w2p,
    float* __restrict__ src, unsigned short* __restrict__ sbf,
    float2* __restrict__ trig,
    unsigned int* __restrict__ qkvspan,
    unsigned short* __restrict__ padA, unsigned short* __restrict__ padB,
    unsigned short* __restrict__ padC)
{
    int idx = blockIdx.x * 256 + threadIdx.x;
    if (idx < R1) {
        int which = idx >> 18;
        const float* W = (which == 0) ? Wq : (which == 1) ? Wk : (which == 2) ? Wv : Wo;
        int rem = idx & 262143;
        int m = rem >> 16;
        int rc = rem & 65535;
        int r = rc >> 8, c = rc & 255;
        float v = (r < 240 && c < 240) ? W[((size_t)m * 240 + r) * 240 + c] : 0.f;
        wqkv[idx] = f2bf(v);
    } else if (idx < R2) {
        int rem = idx - R1;
        int m = rem >> 18;
        int rc = rem & 262143;
        int r = rc >> 8, c = rc & 255;
        float v = (c < 240) ? W1[((size_t)m * 1024 + r) * 240 + c] : 0.f;
        w1p[rem] = f2bf(v);
    } else if (idx < R3) {
        int rem = idx - R2;
        int m = rem >> 18;
        int rc = rem & 262143;
        int r = rc >> 10, c = rc & 1023;
        float v = (r < 240) ? W2[((size_t)m * 240 + r) * 1024 + c] : 0.f;
        w2p[rem] = f2bf(v);
    } else if (idx < R4) {
        // suffix embed: s'=0 state_t, 1 hand_pose_t, 2 head_pose_t, 3..258 hand_t, 259..514 head_t
        int rem = idx - R3;
        int d = rem % cD;
        int r = rem / cD;
        int b = r / cS2, s = r % cS2;
        const float* p; int off;
        if (s == 0)          { p = state_t;      off = b * cD + d; }
        else if (s == 1)     { p = hand_pose_t;  off = b * cD + d; }
        else if (s == 2)     { p = head_pose_t;  off = b * cD + d; }
        else if (s < 259)    { p = hand_t;       off = (b * cN + (s - 3)) * cD + d; }
        else                 { p = head_t;       off = (b * cN + (s - 259)) * cD + d; }
        float v = p[off];
        src[rem] = v;
        sbf[(size_t)r * cKp + d] = f2bf(v);
    } else if (idx < R5) {
        int rem = idx - R4;
        int r = rem / 15, pair = rem - r * 15;
        int b = r / cS2, s = r % cS2;
        int a = pair / 5, j = pair - a * 5;
        float coord = 0.f;
        if (s >= 3 && s < 259)       coord = ch_t[(b * cN + (s - 3)) * 3 + a];
        else if (s >= 259)           coord = cd_t[(b * cN + (s - 259)) * 3 + a];
        float inv = __expf(-1.8420680743952367f * (float)j);
        float sn, co;
        sincosf(coord * inv, &sn, &co);
        trig[rem] = make_float2(co, sn);
    } else if (idx < R6) {
        qkvspan[idx - R5] = 0u;
    } else if (idx < R7) {
        int rem = idx - R6;
        int r = rem >> 3, j = rem & 7;
        ((unsigned int*)(padA + (size_t)r * 256 + 240))[j] = 0u;
        ((unsigned int*)(padB + (size_t)r * 256 + 240))[j] = 0u;
        ((unsigned int*)(padC + (size_t)r * 256 + 240))[j] = 0u;
    }
}

// ======== MFMA GEMM core, BM=64/BN=64, BK=64, wave tile 32x32 ========
#define GEMM_CORE64(A_PTR, W_PTR, M_, KA_, NK_)                                               \
    __shared__ unsigned short Al[64][72];                                                     \
    __shared__ unsigned short Bl[64][72];                                                     \
    const int tid = threadIdx.x;                                                              \
    const int lane = tid & 63;                                                                \
    const int w = tid >> 6;                                                                   \
    const int wm = w >> 1, wn = w & 1;                                                        \
    const int lrow = lane & 15, kq = lane >> 4;                                               \
    const int colBase = blockIdx.x * 64;                                                      \
    const int sRow = tid >> 2;                                                                \
    const int sC = (tid & 3) * 16;                                                            \
    const int ar0 = min(rowBase + sRow, M_ - 1);                                              \
    const int wr = colBase + sRow;                                                            \
    const unsigned short* a0p = A_PTR + (size_t)ar0 * KA_ + sC;                               \
    const unsigned short* wp  = W_PTR + (size_t)wr * KA_ + sC;                                \
    f32x4 acc[2][2] = {};                                                                     \
    int4 rA0a = *(const int4*)a0p, rA0b = *(const int4*)(a0p + 8);                            \
    int4 rBa  = *(const int4*)wp,  rBb  = *(const int4*)(wp + 8);                             \
    for (int ks = 0; ks < NK_; ++ks) {                                                        \
        __syncthreads();                                                                      \
        *(int4*)&Al[sRow][sC]     = rA0a;                                                     \
        *(int4*)&Al[sRow][sC + 8] = rA0b;                                                     \
        *(int4*)&Bl[sRow][sC]     = rBa;                                                      \
        *(int4*)&Bl[sRow][sC + 8] = rBb;                                                      \
        __syncthreads();                                                                      \
        if (ks + 1 < NK_) {                                                                   \
            int kk = (ks + 1) * 64;                                                           \
            rA0a = *(const int4*)(a0p + kk); rA0b = *(const int4*)(a0p + kk + 8);             \
            rBa  = *(const int4*)(wp + kk);  rBb  = *(const int4*)(wp + kk + 8);              \
        }                                                                                     \
        _Pragma("unroll")                                                                     \
        for (int sub = 0; sub < 2; ++sub) {                                                   \
            bf16x8 af[2], bfr[2];                                                             \
            _Pragma("unroll")                                                                 \
            for (int i = 0; i < 2; ++i)                                                       \
                af[i] = *(const bf16x8*)&Al[wm * 32 + i * 16 + lrow][sub * 32 + kq * 8];      \
            _Pragma("unroll")                                                                 \
            for (int j = 0; j < 2; ++j)                                                       \
                bfr[j] = *(const bf16x8*)&Bl[wn * 32 + j * 16 + lrow][sub * 32 + kq * 8];     \
            _Pragma("unroll")                                                                 \
            for (int i = 0; i < 2; ++i)                                                       \
                _Pragma("unroll")                                                             \
                for (int j = 0; j < 2; ++j)                                                   \
                    acc[i][j] = __builtin_amdgcn_mfma_f32_16x16x32_bf16(af[i], bfr[j], acc[i][j], 0, 0, 0); \
        }                                                                                     \
    }

// ------- QKV GEMM (BM=64) with fused RoPE; bf16 q,k (BH,SP2,32) and V^T (BH,32,SP2) -------
__global__ __launch_bounds__(256) void gemm_qkv_rope(
    const unsigned short* __restrict__ A,
    const unsigned short* __restrict__ Wqp, const unsigned short* __restrict__ Wkp,
    const unsigned short* __restrict__ Wvp,
    const float* __restrict__ bq, const float* __restrict__ bk, const float* __restrict__ bv,
    const float2* __restrict__ trig,
    unsigned short* __restrict__ qbf, unsigned short* __restrict__ kbf,
    unsigned short* __restrict__ vtbf)
{
    const int z = blockIdx.z;
    const unsigned short* Wsel = (z == 0) ? Wqp : (z == 1) ? Wkp : Wvp;
    const float* bias = (z == 0) ? bq : (z == 1) ? bk : bv;
    const int rowBase = blockIdx.y * 64;
    GEMM_CORE64(A, Wsel, cBS2, cKp, 4)
    if (z == 2) {
#pragma unroll
        for (int i = 0; i < 2; ++i) {
#pragma unroll
            for (int j = 0; j < 2; ++j) {
                int col = colBase + wn * 32 + j * 16 + lrow;
                if (col >= cD) continue;
                float bcol = bias[col];
                int hh = col / cHD, hd = col % cHD;
                f32x4 vv = acc[i][j];
                int row0 = rowBase + wm * 32 + i * 16 + kq * 4;
                int b0 = row0 / cS2, s0 = row0 - b0 * cS2;
                if (row0 + 3 < cBS2 && s0 + 3 < cS2) {
                    unsigned int lo = (unsigned)f2bf(vv[0] + bcol) | ((unsigned)f2bf(vv[1] + bcol) << 16);
                    unsigned int hi = (unsigned)f2bf(vv[2] + bcol) | ((unsigned)f2bf(vv[3] + bcol) << 16);
                    size_t base = ((size_t)(b0 * cH + hh) * 32 + hd) * cSP2 + s0;
                    *(unsigned int*)&vtbf[base]     = lo;
                    *(unsigned int*)&vtbf[base + 2] = hi;
                } else {
#pragma unroll
                    for (int r = 0; r < 4; ++r) {
                        int row = row0 + r;
                        if (row >= cBS2) continue;
                        int bb = row / cS2, ss = row - bb * cS2;
                        vtbf[((size_t)(bb * cH + hh) * 32 + hd) * cSP2 + ss] = f2bf(vv[r] + bcol);
                    }
                }
            }
        }
    } else {
        unsigned short* dst = (z == 0) ? qbf : kbf;
#pragma unroll
        for (int i = 0; i < 2; ++i) {
#pragma unroll
            for (int j = 0; j < 2; ++j) {
                int col = colBase + wn * 32 + j * 16 + lrow;
                bool colok = col < cD;
                int cc = colok ? col : 0;
                float bcol = colok ? bias[cc] : 0.f;
                int hh = cc / cHD, hd = cc % cHD;
                int a3 = hd / 10, jj = (hd % 10) >> 1;
                int pair = a3 * 5 + jj;
                f32x4 vv = acc[i][j];
#pragma unroll
                for (int r = 0; r < 4; ++r) {
                    int row = rowBase + wm * 32 + i * 16 + kq * 4 + r;
                    bool rowok = row < cBS2;
                    int rowc = rowok ? row : 0;
                    float val = vv[r] + bcol;
                    float pval = __shfl_xor(val, 1);   // partner col (pairs are adjacent lanes)
                    float2 t = trig[rowc * 15 + pair];
                    float outv = (hd & 1) ? (pval * t.y + val * t.x) : (val * t.x - pval * t.y);
                    if (colok && rowok) {
                        int b = rowc / cS2, s = rowc - b * cS2;
                        dst[((size_t)(b * cH + hh) * cSP2 + s) * 32 + hd] = f2bf(outv);
                    }
                }
            }
        }
    }
}

// ------- MFMA flash attention (unmasked suffix), kv-split x4: 16 q-rows/block -------
__global__ __launch_bounds__(256) void attn_mfma(
    const unsigned short* __restrict__ qbf, const unsigned short* __restrict__ kbf,
    const unsigned short* __restrict__ vtbf, unsigned short* __restrict__ outb)
{
    __shared__ unsigned short Pl[4][16][72];
    __shared__ float Ol[4][16][33];
    __shared__ float Ml[4][16];
    __shared__ float Ll[4][16];
    const int tid = threadIdx.x, lane = tid & 63, w = tid >> 6;
    const int bh = blockIdx.y, b = bh >> 3, h = bh & 7;
    const int qbase = blockIdx.x * 16;
    const int lr = lane & 15, lg = lane >> 4;
    const float scl = 0.18257418583505536f; // 1/sqrt(30)
    const f32x4 czero = {0.f, 0.f, 0.f, 0.f};
    bf16x8 qf = *(const bf16x8*)&qbf[((size_t)bh * cSP2 + qbase + lr) * 32 + lg * 8];
    float m[4], l[4];
    f32x4 o0 = czero, o1 = czero;
#pragma unroll
    for (int r = 0; r < 4; ++r) { m[r] = -3.0e38f; l[r] = 0.f; }
    const int ts = (w * 9) / 4;        // 9 key tiles split over 4 waves
    const int te = ((w + 1) * 9) / 4;
    for (int tt = ts; tt < te; ++tt) {
        const int kb = tt * 64;
        f32x4 c[4];
#pragma unroll
        for (int t = 0; t < 4; ++t) {
            bf16x8 kf = *(const bf16x8*)&kbf[((size_t)bh * cSP2 + kb + 16 * t + lr) * 32 + lg * 8];
            c[t] = __builtin_amdgcn_mfma_f32_16x16x32_bf16(qf, kf, czero, 0, 0, 0);
        }
#pragma unroll
        for (int t = 0; t < 4; ++t) {
            bool koob = (kb + 16 * t + lr) >= cS2;
#pragma unroll
            for (int r = 0; r < 4; ++r)
                c[t][r] = koob ? -3.0e38f : c[t][r] * scl;
        }
        float mx[4];
#pragma unroll
        for (int r = 0; r < 4; ++r)
            mx[r] = fmaxf(fmaxf(c[0][r], c[1][r]), fmaxf(c[2][r], c[3][r]));
#pragma unroll
        for (int off = 1; off < 16; off <<= 1)
#pragma unroll
            for (int r = 0; r < 4; ++r)
                mx[r] = fmaxf(mx[r], __shfl_xor(mx[r], off));
        float corr[4], me[4], ps[4];
#pragma unroll
        for (int r = 0; r < 4; ++r) {
            float mn = fmaxf(m[r], mx[r]);
            corr[r] = __expf(m[r] - mn);
            m[r] = mn;
            me[r] = fmaxf(mn, -1.0e30f);
            ps[r] = 0.f;
        }
#pragma unroll
        for (int t = 0; t < 4; ++t)
#pragma unroll
            for (int r = 0; r < 4; ++r) {
                float p = __expf(c[t][r] - me[r]);
                c[t][r] = p;
                ps[r] += p;
            }
#pragma unroll
        for (int off = 1; off < 16; off <<= 1)
#pragma unroll
            for (int r = 0; r < 4; ++r)
                ps[r] += __shfl_xor(ps[r], off);
#pragma unroll
        for (int r = 0; r < 4; ++r) {
            l[r] = l[r] * corr[r] + ps[r];
            o0[r] *= corr[r];
            o1[r] *= corr[r];
        }
#pragma unroll
        for (int t = 0; t < 4; ++t)
#pragma unroll
            for (int r = 0; r < 4; ++r)
                Pl[w][lg * 4 + r][16 * t + lr] = f2bf(c[t][r]);
#pragma unroll
        for (int c2 = 0; c2 < 2; ++c2) {
            bf16x8 pa  = *(const bf16x8*)&Pl[w][lr][c2 * 32 + lg * 8];
            bf16x8 bv0 = *(const bf16x8*)&vtbf[((size_t)bh * 32 + lr) * cSP2 + kb + c2 * 32 + lg * 8];
            bf16x8 bv1 = *(const bf16x8*)&vtbf[((size_t)bh * 32 + 16 + lr) * cSP2 + kb + c2 * 32 + lg * 8];
            o0 = __builtin_amdgcn_mfma_f32_16x16x32_bf16(pa, bv0, o0, 0, 0, 0);
            o1 = __builtin_amdgcn_mfma_f32_16x16x32_bf16(pa, bv1, o1, 0, 0, 0);
        }
    }
#pragma unroll
    for (int r = 0; r < 4; ++r) {
        int row = lg * 4 + r;
        if (lr == 0) { Ml[w][row] = m[r]; Ll[w][row] = l[r]; }
        Ol[w][row][lr]      = o0[r];
        Ol[w][row][16 + lr] = o1[r];
    }
    __syncthreads();
    if (w == 0) {
        const int col = lane & 31, half = lane >> 5;
#pragma unroll
        for (int rr = 0; rr < 8; ++rr) {
            int row = half * 8 + rr;
            float M = fmaxf(fmaxf(Ml[0][row], Ml[1][row]), fmaxf(Ml[2][row], Ml[3][row]));
            float Lt = 0.f, Ot = 0.f;
#pragma unroll
            for (int ww = 0; ww < 4; ++ww) {
                float cc = __expf(Ml[ww][row] - M);
                Lt += Ll[ww][row] * cc;
                Ot += Ol[ww][row][col] * cc;
            }
            int qq = qbase + row;
            if (qq < cS2 && col < cHD)
                outb[((size_t)(b * cS2 + qq)) * cKp + h * cHD + col] = f2bf(Ot / Lt);
        }
    }
}

// ------- BM=64 GEMM + bias + residual -> f32 (O-proj) -------
__global__ __launch_bounds__(256) void gemm_res64(
    const unsigned short* __restrict__ A, const unsigned short* __restrict__ W,
    const float* __restrict__ bias, const float* __restrict__ Rs,
    float* __restrict__ outF)
{
    const int rowBase = blockIdx.y * 64;
    GEMM_CORE64(A, W, cBS2, cKp, 4)
#pragma unroll
    for (int i = 0; i < 2; ++i) {
#pragma unroll
        for (int j = 0; j < 2; ++j) {
            int col = colBase + wn * 32 + j * 16 + lrow;
            if (col >= cD) continue;
            float bcol = bias[col];
            f32x4 v = acc[i][j];
#pragma unroll
            for (int r = 0; r < 4; ++r) {
                int row = rowBase + wm * 32 + i * 16 + kq * 4 + r;
                if (row >= cBS2) continue;
                outF[(size_t)row * cD + col] = v[r] + bcol + Rs[(size_t)row * cD + col];
            }
        }
    }
}

// ------- FF1 GEMM (BM=64): gelu(+bias) -> bf16 (ld 1024) -------
__global__ __launch_bounds__(256) void gemm_ff1(
    const unsigned short* __restrict__ A, const unsigned short* __restrict__ W,
    const float* __restrict__ bias, unsigned short* __restrict__ outB)
{
    const int rowBase = blockIdx.y * 64;
    GEMM_CORE64(A, W, cBS2, cKp, 4)
#pragma unroll
    for (int i = 0; i < 2; ++i) {
#pragma unroll
        for (int j = 0; j < 2; ++j) {
            int col = colBase + wn * 32 + j * 16 + lrow;
            float bcol = bias[col];
            f32x4 v = acc[i][j];
#pragma unroll
            for (int r = 0; r < 4; ++r) {
                int row = rowBase + wm * 32 + i * 16 + kq * 4 + r;
                if (row >= cBS2) continue;
                float t = v[r] + bcol;
                float gl = 0.5f * t * (1.0f + erff(t * 0.70710678118654752f));
                outB[(size_t)row * 1024 + col] = f2bf(gl);
            }
        }
    }
}

// ------- FF2 split-K partial: P[z] = gelu_act @ W2[:, z*512:(z+1)*512]^T (no bias) -------
__global__ __launch_bounds__(256) void gemm_ff2_part(
    const unsigned short* __restrict__ A, const unsigned short* __restrict__ W,
    float* __restrict__ p0, float* __restrict__ p1)
{
    const int z = blockIdx.z;
    const int rowBase = blockIdx.y * 64;
    const unsigned short* Ap = A + z * 512;
    const unsigned short* Wp = W + z * 512;
    float* pF = z ? p1 : p0;
    GEMM_CORE64(Ap, Wp, cBS2, cFF, 8)
#pragma unroll
    for (int i = 0; i < 2; ++i) {
#pragma unroll
        for (int j = 0; j < 2; ++j) {
            int col = colBase + wn * 32 + j * 16 + lrow;
            if (col >= cD) continue;
            f32x4 v = acc[i][j];
#pragma unroll
            for (int r = 0; r < 4; ++r) {
                int row = rowBase + wm * 32 + i * 16 + kq * 4 + r;
                if (row >= cBS2) continue;
                pF[(size_t)row * cD + col] = v[r];
            }
        }
    }
}

// ---------------- LayerNorm helpers (float4, one row per wave) ----------------
__device__ inline void ln_core(float4 v, const float* __restrict__ g,
                               const float* __restrict__ be, float* __restrict__ yr,
                               unsigned short* __restrict__ br, int lane, bool ok)
{
    float sum = v.x + v.y + v.z + v.w;
#pragma unroll
    for (int off = 1; off < 64; off <<= 1) sum += __shfl_xor(sum, off);
    float mean = sum * (1.0f / cD);
    float vs = 0.f;
    if (ok) {
        float dx = v.x - mean, dy = v.y - mean, dz = v.z - mean, dw = v.w - mean;
        vs = dx * dx + dy * dy + dz * dz + dw * dw;
    }
#pragma unroll
    for (int off = 1; off < 64; off <<= 1) vs += __shfl_xor(vs, off);
    float rstd = rsqrtf(vs * (1.0f / cD) + EPSF);
    if (ok) {
        float4 g4 = *(const float4*)(g + 4 * lane);
        float4 b4 = *(const float4*)(be + 4 * lane);
        float4 y;
        y.x = (v.x - mean) * rstd * g4.x + b4.x;
        y.y = (v.y - mean) * rstd * g4.y + b4.y;
        y.z = (v.z - mean) * rstd * g4.z + b4.z;
        y.w = (v.w - mean) * rstd * g4.w + b4.w;
        *(float4*)(yr + 4 * lane) = y;
        if (br) {
            uint2 pk;
            pk.x = (unsigned)f2bf(y.x) | ((unsigned)f2bf(y.y) << 16);
            pk.y = (unsigned)f2bf(y.z) | ((unsigned)f2bf(y.w) << 16);
            *(uint2*)(br + 4 * lane) = pk;
        }
    }
}

// LN1 -> f32 (ld 240) + bf16 (ld 256)
__global__ __launch_bounds__(256) void ln_kernel(
    const float* __restrict__ x, const float* __restrict__ g,
    const float* __restrict__ be, float* __restrict__ y, unsigned short* __restrict__ ybf)
{
    int row = blockIdx.x * 4 + (threadIdx.x >> 6);
    int lane = threadIdx.x & 63;
    if (row >= cBS2) return;
    bool ok = lane < 60;
    float4 v = make_float4(0.f, 0.f, 0.f, 0.f);
    if (ok) v = *(const float4*)(x + (size_t)row * cD + 4 * lane);
    ln_core(v, g, be, y + (size_t)row * cD, ybf + (size_t)row * cKp, lane, ok);
}

// LN2: combine FF2 partials + residual + bias, then LN -> f32 + bf16
__global__ __launch_bounds__(256) void ln2_kernel(
    const float* __restrict__ s2, const float* __restrict__ p0, const float* __restrict__ p1,
    const float* __restrict__ b2, const float* __restrict__ g, const float* __restrict__ be,
    float* __restrict__ y, unsigned short* __restrict__ ybf)
{
    int row = blockIdx.x * 4 + (threadIdx.x >> 6);
    int lane = threadIdx.x & 63;
    if (row >= cBS2) return;
    bool ok = lane < 60;
    float4 v = make_float4(0.f, 0.f, 0.f, 0.f);
    if (ok) {
        float4 a  = *(const float4*)(s2 + (size_t)row * cD + 4 * lane);
        float4 q0 = *(const float4*)(p0 + (size_t)row * cD + 4 * lane);
        float4 q1 = *(const float4*)(p1 + (size_t)row * cD + 4 * lane);
        float4 bb = *(const float4*)(b2 + 4 * lane);
        v.x = a.x + q0.x + q1.x + bb.x;
        v.y = a.y + q0.y + q1.y + bb.y;
        v.z = a.z + q0.z + q1.z + bb.z;
        v.w = a.w + q0.w + q1.w + bb.w;
    }
    ln_core(v, g, be, y + (size_t)row * cD, ybf + (size_t)row * cKp, lane, ok);
}

// final LN2: all suffix rows straight into d_out (layouts coincide)
__global__ __launch_bounds__(256) void ln2_final(
    const float* __restrict__ s2, const float* __restrict__ p0, const float* __restrict__ p1,
    const float* __restrict__ b2, const float* __restrict__ g, const float* __restrict__ be,
    float* __restrict__ out)
{
    int row = blockIdx.x * 4 + (threadIdx.x >> 6);
    int lane = threadIdx.x & 63;
    if (row >= cBS2) return;
    bool ok = lane < 60;
    float4 v = make_float4(0.f, 0.f, 0.f, 0.f);
    if (ok) {
        float4 a  = *(const float4*)(s2 + (size_t)row * cD + 4 * lane);
        float4 q0 = *(const float4*)(p0 + (size_t)row * cD + 4 * lane);
        float4 q1 = *(const float4*)(p1 + (size_t)row * cD + 4 * lane);
        float4 bb = *(const float4*)(b2 + 4 * lane);
        v.x = a.x + q0.x + q1.x + bb.x;
        v.y = a.y + q0.y + q1.y + bb.y;
        v.z = a.z + q0.z + q1.z + bb.z;
        v.w = a.w + q0.w + q1.w + bb.w;
    }
    ln_core(v, g, be, out + (size_t)row * cD, nullptr, lane, ok);
}

extern "C" void kernel_launch(void* const* d_in, const int* in_sizes, int n_in,
                              void* d_out, int out_size, void* d_ws, size_t ws_size,
                              hipStream_t stream) {
    (void)in_sizes; (void)n_in; (void)out_size; (void)ws_size;
    const float* hand_t       = (const float*)d_in[0];
    const float* head_t       = (const float*)d_in[1];
    const float* c_hand_t     = (const float*)d_in[4];
    const float* c_head_t     = (const float*)d_in[5];
    const float* state_t      = (const float*)d_in[8];
    const float* hand_pose_t  = (const float*)d_in[12];
    const float* head_pose_t  = (const float*)d_in[13];
    const float* Wq = (const float*)d_in[14];
    const float* Wk = (const float*)d_in[15];
    const float* Wv = (const float*)d_in[16];
    const float* Wo = (const float*)d_in[17];
    const float* W1 = (const float*)d_in[18];
    const float* W2 = (const float*)d_in[19];
    const float* bq = (const float*)d_in[20];
    const float* bk = (const float*)d_in[21];
    const float* bv = (const float*)d_in[22];
    const float* bo = (const float*)d_in[23];
    const float* b1 = (const float*)d_in[24];
    const float* b2 = (const float*)d_in[25];
    const float* g1 = (const float*)d_in[26];
    const float* be1 = (const float*)d_in[27];
    const float* g2 = (const float*)d_in[28];
    const float* be2 = (const float*)d_in[29];

    // ---- workspace layout ----
    char* p = (char*)d_ws;
    auto alloc_f = [&](size_t n) { float* r = (float*)p; p += n * sizeof(float); return r; };
    auto alloc_h = [&](size_t n) { unsigned short* r = (unsigned short*)p; p += n * sizeof(unsigned short); return r; };
    float* srcb  = alloc_f((size_t)cBS2 * cD);
    float* s2b   = alloc_f((size_t)cBS2 * cD);
    float* resid = alloc_f((size_t)cBS2 * cD);   // O-proj residual; reused as FF2 partial 0
    float* part1 = alloc_f((size_t)cBS2 * cD);   // FF2 partial 1
    float* trigf = alloc_f((size_t)cBS2 * 15 * 2);
    unsigned short* src_bf  = alloc_h((size_t)cBS2 * cKp);
    unsigned short* s2_bf   = alloc_h((size_t)cBS2 * cKp);
    unsigned short* attn_bf = alloc_h((size_t)cBS2 * cKp);
    unsigned short* ff_bf   = alloc_h((size_t)cBS2 * cFF);
    unsigned short* qbf  = alloc_h(qkvN);
    unsigned short* kbf  = alloc_h(qkvN);
    unsigned short* vtbf = alloc_h(qkvN);
    unsigned short* wqkv = alloc_h((size_t)4 * cL * 65536);
    unsigned short* w1p  = alloc_h((size_t)cL * 1024 * 256);
    unsigned short* w2p  = alloc_h((size_t)cL * 256 * 1024);
    float2* trig = (float2*)trigf;

    // ---- setup (single dispatch) ----
    setup_all<<<(R7 + 255) / 256, 256, 0, stream>>>(
        Wq, Wk, Wv, Wo, W1, W2,
        hand_t, head_t, state_t, hand_pose_t, head_pose_t,
        c_hand_t, c_head_t,
        wqkv, w1p, w2p, srcb, src_bf, trig,
        (unsigned int*)qbf, src_bf, s2_bf, attn_bf);

    const int mT = (cBS2 + 63) / 64;   // 33
    for (int l = 0; l < cL; ++l) {
        const unsigned short* wq_l = wqkv + (size_t)(0 * cL + l) * 65536;
        const unsigned short* wk_l = wqkv + (size_t)(1 * cL + l) * 65536;
        const unsigned short* wv_l = wqkv + (size_t)(2 * cL + l) * 65536;
        const unsigned short* wo_l = wqkv + (size_t)(3 * cL + l) * 65536;
        const unsigned short* w1_l = w1p + (size_t)l * 1024 * 256;
        const unsigned short* w2_l = w2p + (size_t)l * 256 * 1024;
        const float* bq_l = bq + (size_t)l * cD;
        const float* bk_l = bk + (size_t)l * cD;
        const float* bv_l = bv + (size_t)l * cD;
        const float* bo_l = bo + (size_t)l * cD;
        const float* b1_l = b1 + (size_t)l * cFF;
        const float* b2_l = b2 + (size_t)l * cD;
        const float* g1_l = g1 + (size_t)l * cD;
        const float* be1_l = be1 + (size_t)l * cD;
        const float* g2_l = g2 + (size_t)l * cD;
        const float* be2_l = be2 + (size_t)l * cD;

        gemm_qkv_rope<<<dim3(4, mT, 3), 256, 0, stream>>>(
            src_bf, wq_l, wk_l, wv_l, bq_l, bk_l, bv_l, trig, qbf, kbf, vtbf);
        attn_mfma<<<dim3((cS2 + 15) / 16, cB * cH), 256, 0, stream>>>(
            qbf, kbf, vtbf, attn_bf);
        gemm_res64<<<dim3(4, mT), 256, 0, stream>>>(
            attn_bf, wo_l, bo_l, srcb, resid);
        ln_kernel<<<(cBS2 + 3) / 4, 256, 0, stream>>>(resid, g1_l, be1_l, s2b, s2_bf);
        gemm_ff1<<<dim3(16, mT), 256, 0, stream>>>(s2_bf, w1_l, b1_l, ff_bf);
        gemm_ff2_part<<<dim3(4, mT, 2), 256, 0, stream>>>(ff_bf, w2_l, resid, part1);
        if (l < cL - 1) {
            ln2_kernel<<<(cBS2 + 3) / 4, 256, 0, stream>>>(
                s2b, resid, part1, b2_l, g2_l, be2_l, srcb, src_bf);
        } else {
            ln2_final<<<(cBS2 + 3) / 4, 256, 0, stream>>>(
                s2b, resid, part1, b2_l, g2_l, be2_l, (float*)d_out);
        }
    }
}